// Round 2
// baseline (591.924 us; speedup 1.0000x reference)
//
#include <hip/hip_runtime.h>

// LoRALinear: out = x @ (W + (alpha/rank) * B@A)^T + b
// x: [8192, 4096] f32, W: [4096, 4096] f32, b: [4096] f32,
// lora_A: [16, 4096] f32, lora_B: [4096, 16] f32, out: [8192, 4096] f32
// Strategy: fold LoRA into W' (bf16), convert x to bf16, one MFMA GEMM.

static constexpr int Mdim = 8192;
static constexpr int Ndim = 4096;
static constexpr int Kdim = 4096;
#define LORA_SCALE 2.0f   // alpha/rank = 32/16

typedef __bf16 bf16;
typedef __bf16 bf16x8 __attribute__((ext_vector_type(8)));
typedef __bf16 bf16x4 __attribute__((ext_vector_type(4)));
typedef float f32x4 __attribute__((ext_vector_type(4)));

__device__ __forceinline__ void gload_lds16(const void* g, void* l) {
  __builtin_amdgcn_global_load_lds(
      (const __attribute__((address_space(1))) unsigned int*)g,
      (__attribute__((address_space(3))) unsigned int*)l, 16, 0, 0);
}

// ---------------- kernel 1: x fp32 -> bf16 ----------------
__global__ __launch_bounds__(256) void cvt_x_kernel(const float* __restrict__ x,
                                                    bf16* __restrict__ xb, int n8) {
  for (int i = blockIdx.x * blockDim.x + threadIdx.x; i < n8;
       i += gridDim.x * blockDim.x) {
    const float4* p = reinterpret_cast<const float4*>(x) + (size_t)i * 2;
    float4 a = p[0];
    float4 c = p[1];
    bf16x8 o;
    o[0] = (bf16)a.x; o[1] = (bf16)a.y; o[2] = (bf16)a.z; o[3] = (bf16)a.w;
    o[4] = (bf16)c.x; o[5] = (bf16)c.y; o[6] = (bf16)c.z; o[7] = (bf16)c.w;
    reinterpret_cast<bf16x8*>(xb)[i] = o;
  }
}

// ---------------- kernel 2: W' = W + 2*B@A  (bf16) ----------------
// 8 output rows per block; A row segments shared across the 8 rows.
__global__ __launch_bounds__(256) void build_w_kernel(const float* __restrict__ W,
                                                      const float* __restrict__ lA,
                                                      const float* __restrict__ lB,
                                                      bf16* __restrict__ wb) {
  const int n0 = blockIdx.x * 8;
  const int t = threadIdx.x;
  __shared__ float bs[8][16];
  if (t < 128) bs[t >> 4][t & 15] = lB[(n0 + (t >> 4)) * 16 + (t & 15)] * LORA_SCALE;
  __syncthreads();
  for (int k0 = t * 4; k0 < Kdim; k0 += 1024) {
    float4 acc[8];
#pragma unroll
    for (int j = 0; j < 8; ++j)
      acc[j] = *reinterpret_cast<const float4*>(&W[(size_t)(n0 + j) * Kdim + k0]);
#pragma unroll
    for (int r = 0; r < 16; ++r) {
      float4 a = *reinterpret_cast<const float4*>(&lA[r * Kdim + k0]);
#pragma unroll
      for (int j = 0; j < 8; ++j) {
        acc[j].x += bs[j][r] * a.x;
        acc[j].y += bs[j][r] * a.y;
        acc[j].z += bs[j][r] * a.z;
        acc[j].w += bs[j][r] * a.w;
      }
    }
#pragma unroll
    for (int j = 0; j < 8; ++j) {
      bf16x4 o;
      o[0] = (bf16)acc[j].x; o[1] = (bf16)acc[j].y;
      o[2] = (bf16)acc[j].z; o[3] = (bf16)acc[j].w;
      *reinterpret_cast<bf16x4*>(&wb[(size_t)(n0 + j) * Kdim + k0]) = o;
    }
  }
}

// ---------------- kernel 3: bf16 MFMA GEMM  C = Xb @ Wb^T + bias ----------------
// m97 structure: 128x128 tile, BK=32, 4 waves (2x2), 4x4 16x16x32 frags/wave,
// K-major LDS [kc][row][8] (linear for global_load_lds, conflict-free ds_read_b128).
__global__ __launch_bounds__(256) void gemm_bf16(const bf16* __restrict__ Xb,
                                                 const bf16* __restrict__ Wb,
                                                 const float* __restrict__ bias,
                                                 float* __restrict__ out) {
  __shared__ alignas(16) bf16 As[4][128][8];  // 8 KB: A[m][kt*32 + kc*8 + j] at [kc][m][j]
  __shared__ alignas(16) bf16 Bs[4][128][8];  // 8 KB
  const int t = threadIdx.x;
  const int lane = t & 63;
  const int w = t >> 6;
  const int wm = w >> 1, wn = w & 1;           // 2x2 wave grid, 64x64 per wave
  const int bm0 = blockIdx.y * 128;
  const int bn0 = blockIdx.x * 128;
  const int kc = lane >> 4, r16 = lane & 15;

  f32x4 acc[4][4] = {};

  const bf16x8* aF[4];
  const bf16x8* bF[4];
#pragma unroll
  for (int mi = 0; mi < 4; ++mi)
    aF[mi] = reinterpret_cast<const bf16x8*>(&As[kc][wm * 64 + mi * 16 + r16][0]);
#pragma unroll
  for (int nj = 0; nj < 4; ++nj)
    bF[nj] = reinterpret_cast<const bf16x8*>(&Bs[kc][wn * 64 + nj * 16 + r16][0]);

  // staging: slot p in [0,512): element chunk [kc=p>>7][row=p&127]; thread t owns p=t, p=t+256
  const size_t arow = (size_t)(bm0 + (t & 127));
  const size_t brow = (size_t)(bn0 + (t & 127));
  const int kca = (t >> 7) * 8;
  const bf16* aSrc = Xb + arow * Kdim + kca;
  const bf16* bSrc = Wb + brow * Kdim + kca;
  char* ldsA = (char*)(&As[0][0][0]) + t * 16;
  char* ldsB = (char*)(&Bs[0][0][0]) + t * 16;

  for (int kt = 0; kt < Kdim; kt += 32) {
    gload_lds16(aSrc + kt, ldsA);
    gload_lds16(aSrc + kt + 16, ldsA + 4096);
    gload_lds16(bSrc + kt, ldsB);
    gload_lds16(bSrc + kt + 16, ldsB + 4096);
    __syncthreads();  // drains vmcnt -> tile ready
    bf16x8 av[4], bv[4];
#pragma unroll
    for (int mi = 0; mi < 4; ++mi) av[mi] = *aF[mi];
#pragma unroll
    for (int nj = 0; nj < 4; ++nj) bv[nj] = *bF[nj];
#pragma unroll
    for (int mi = 0; mi < 4; ++mi)
#pragma unroll
      for (int nj = 0; nj < 4; ++nj)
        acc[mi][nj] = __builtin_amdgcn_mfma_f32_16x16x32_bf16(av[mi], bv[nj],
                                                              acc[mi][nj], 0, 0, 0);
    __syncthreads();  // all waves done reading LDS before next stage
  }

  // epilogue: C/D layout col=lane&15, row=(lane>>4)*4+reg
  const int crow0 = bm0 + wm * 64 + (lane >> 4) * 4;
  const int ccol0 = bn0 + wn * 64 + r16;
  float bvv[4];
#pragma unroll
  for (int nj = 0; nj < 4; ++nj) bvv[nj] = bias[ccol0 + nj * 16];
#pragma unroll
  for (int mi = 0; mi < 4; ++mi)
#pragma unroll
    for (int nj = 0; nj < 4; ++nj)
#pragma unroll
      for (int r = 0; r < 4; ++r)
        out[(size_t)(crow0 + mi * 16 + r) * Ndim + ccol0 + nj * 16] =
            acc[mi][nj][r] + bvv[nj];
}

// ---------------- fallback (only if ws too small): fp32 tiled GEMM, fold on stage ----------------
__global__ __launch_bounds__(256) void gemm_fallback(const float* __restrict__ x,
                                                     const float* __restrict__ W,
                                                     const float* __restrict__ bias,
                                                     const float* __restrict__ lA,
                                                     const float* __restrict__ lB,
                                                     float* __restrict__ out) {
  __shared__ float xs[16][64];
  __shared__ float wt[16][64];
  const int t = threadIdx.x;
  const int tx = t & 15, ty = t >> 4;
  const int bm0 = blockIdx.y * 64, bn0 = blockIdx.x * 64;
  float acc[4][4] = {};
  for (int kt = 0; kt < Kdim; kt += 16) {
    __syncthreads();
    for (int e = t; e < 1024; e += 256) {
      int m = e >> 4, k = e & 15;
      xs[k][m] = x[(size_t)(bm0 + m) * Kdim + kt + k];
    }
    for (int e = t; e < 1024; e += 256) {
      int n = e >> 4, k = e & 15;
      float v = W[(size_t)(bn0 + n) * Kdim + kt + k];
#pragma unroll
      for (int r = 0; r < 16; ++r)
        v += LORA_SCALE * lB[(bn0 + n) * 16 + r] * lA[r * Kdim + kt + k];
      wt[k][n] = v;
    }
    __syncthreads();
#pragma unroll
    for (int k = 0; k < 16; ++k) {
      float xa[4], wv[4];
#pragma unroll
      for (int i = 0; i < 4; ++i) xa[i] = xs[k][ty * 4 + i];
#pragma unroll
      for (int j = 0; j < 4; ++j) wv[j] = wt[k][tx * 4 + j];
#pragma unroll
      for (int i = 0; i < 4; ++i)
#pragma unroll
        for (int j = 0; j < 4; ++j) acc[i][j] += xa[i] * wv[j];
    }
  }
#pragma unroll
  for (int i = 0; i < 4; ++i)
#pragma unroll
    for (int j = 0; j < 4; ++j)
      out[(size_t)(bm0 + ty * 4 + i) * Ndim + bn0 + tx * 4 + j] =
          acc[i][j] + bias[bn0 + tx * 4 + j];
}

extern "C" void kernel_launch(void* const* d_in, const int* in_sizes, int n_in,
                              void* d_out, int out_size, void* d_ws, size_t ws_size,
                              hipStream_t stream) {
  const float* x = (const float*)d_in[0];
  const float* W = (const float*)d_in[1];
  const float* b = (const float*)d_in[2];
  const float* lA = (const float*)d_in[3];
  const float* lB = (const float*)d_in[4];
  float* out = (float*)d_out;

  const size_t xb_bytes = (size_t)Mdim * Kdim * sizeof(bf16);
  const size_t wb_bytes = (size_t)Ndim * Kdim * sizeof(bf16);

  if (ws_size >= xb_bytes + wb_bytes) {
    bf16* xb = (bf16*)d_ws;
    bf16* wb = (bf16*)((char*)d_ws + xb_bytes);
    cvt_x_kernel<<<4096, 256, 0, stream>>>(x, xb, Mdim * Kdim / 8);
    build_w_kernel<<<Ndim / 8, 256, 0, stream>>>(W, lA, lB, wb);
    dim3 grid(Ndim / 128, Mdim / 128);
    gemm_bf16<<<grid, 256, 0, stream>>>(xb, wb, b, out);
  } else {
    dim3 grid(Ndim / 64, Mdim / 64);
    gemm_fallback<<<grid, 64 * 4, 0, stream>>>(x, W, b, lA, lB, out);
  }
}

// Round 4
// 444.727 us; speedup vs baseline: 1.3310x; 1.3310x over previous
//
#include <hip/hip_runtime.h>

// LoRALinear: out = x @ (W + 2 * B@A)^T + b
// Fold LoRA into W' (bf16), convert x to bf16, one 256x256-tile 8-phase MFMA GEMM.

static constexpr int Mdim = 8192;
static constexpr int Ndim = 4096;
static constexpr int Kdim = 4096;
#define LORA_SCALE 2.0f   // alpha/rank = 32/16

typedef __bf16 bf16;
typedef __bf16 bf16x8 __attribute__((ext_vector_type(8)));
typedef __bf16 bf16x4 __attribute__((ext_vector_type(4)));
typedef float f32x4 __attribute__((ext_vector_type(4)));

__device__ __forceinline__ void gload_lds16(const void* g, void* l) {
  __builtin_amdgcn_global_load_lds(
      (const __attribute__((address_space(1))) unsigned int*)g,
      (__attribute__((address_space(3))) unsigned int*)l, 16, 0, 0);
}

// ---------------- kernel 1: x fp32 -> bf16 ----------------
__global__ __launch_bounds__(256) void cvt_x_kernel(const float* __restrict__ x,
                                                    bf16* __restrict__ xb, int n8) {
  for (int i = blockIdx.x * blockDim.x + threadIdx.x; i < n8;
       i += gridDim.x * blockDim.x) {
    const float4* p = reinterpret_cast<const float4*>(x) + (size_t)i * 2;
    float4 a = p[0];
    float4 c = p[1];
    bf16x8 o;
    o[0] = (bf16)a.x; o[1] = (bf16)a.y; o[2] = (bf16)a.z; o[3] = (bf16)a.w;
    o[4] = (bf16)c.x; o[5] = (bf16)c.y; o[6] = (bf16)c.z; o[7] = (bf16)c.w;
    reinterpret_cast<bf16x8*>(xb)[i] = o;
  }
}

// ---------------- kernel 2: W' = W + 2*B@A  (bf16) ----------------
__global__ __launch_bounds__(256) void build_w_kernel(const float* __restrict__ W,
                                                      const float* __restrict__ lA,
                                                      const float* __restrict__ lB,
                                                      bf16* __restrict__ wb) {
  const int n0 = blockIdx.x * 8;
  const int t = threadIdx.x;
  __shared__ float bs[8][16];
  if (t < 128) bs[t >> 4][t & 15] = lB[(n0 + (t >> 4)) * 16 + (t & 15)] * LORA_SCALE;
  __syncthreads();
  for (int k0 = t * 4; k0 < Kdim; k0 += 1024) {
    float4 acc[8];
#pragma unroll
    for (int j = 0; j < 8; ++j)
      acc[j] = *reinterpret_cast<const float4*>(&W[(size_t)(n0 + j) * Kdim + k0]);
#pragma unroll
    for (int r = 0; r < 16; ++r) {
      float4 a = *reinterpret_cast<const float4*>(&lA[r * Kdim + k0]);
#pragma unroll
      for (int j = 0; j < 8; ++j) {
        acc[j].x += bs[j][r] * a.x;
        acc[j].y += bs[j][r] * a.y;
        acc[j].z += bs[j][r] * a.z;
        acc[j].w += bs[j][r] * a.w;
      }
    }
#pragma unroll
    for (int j = 0; j < 8; ++j) {
      bf16x4 o;
      o[0] = (bf16)acc[j].x; o[1] = (bf16)acc[j].y;
      o[2] = (bf16)acc[j].z; o[3] = (bf16)acc[j].w;
      *reinterpret_cast<bf16x4*>(&wb[(size_t)(n0 + j) * Kdim + k0]) = o;
    }
  }
}

// ---------------- kernel 3: 256x256 8-phase bf16 MFMA GEMM ----------------
// 8 waves (2M x 4N), per-wave 128x64 out. BK=64 split in 2 K-halves of 32.
// LDS 128KB: buf{0,1} x { A: [kh][kc][row 0..255][8bf16] 32KB, B: same 32KB }.
// Stage unit = 16KB half (2 gload_lds16/thread). Cadence per tile t:
//   ph0 -> (t+1) A-k1   ph1 -> (t+1) B-k1   ph2 -> (t+2) A-k0   ph3 -> (t+2) B-k0
// Boundary wait vmcnt(4) (2 halves in flight = next tile's k0), vmcnt(0) at t=63.
#define PHASE_TAIL(NJ0, NJ1)                                                    \
  __builtin_amdgcn_s_barrier();                                                 \
  asm volatile("s_waitcnt lgkmcnt(0)" ::: "memory");                            \
  __builtin_amdgcn_sched_barrier(0);                                            \
  __builtin_amdgcn_s_setprio(1);                                                \
  _Pragma("unroll")                                                             \
  for (int mi = 0; mi < 8; ++mi) {                                              \
    acc[mi][NJ0] = __builtin_amdgcn_mfma_f32_16x16x32_bf16(a[mi], b0,           \
                                                           acc[mi][NJ0], 0, 0, 0); \
    acc[mi][NJ1] = __builtin_amdgcn_mfma_f32_16x16x32_bf16(a[mi], b1,           \
                                                           acc[mi][NJ1], 0, 0, 0); \
  }                                                                             \
  __builtin_amdgcn_s_setprio(0);                                                \
  __builtin_amdgcn_s_barrier();

__global__ __launch_bounds__(512, 2) void gemm8(const bf16* __restrict__ Xb,
                                                const bf16* __restrict__ Wb,
                                                const float* __restrict__ bias,
                                                float* __restrict__ out) {
  extern __shared__ char smem[];  // 131072 bytes
  const int tid = threadIdx.x;
  const int lane = tid & 63;
  const int wid = tid >> 6;
  const int wm = wid >> 2, wn = wid & 3;  // 2 x 4 wave grid
  const int r16 = lane & 15;

  // XCD-aware bijective swizzle (512 wgs, 512 % 8 == 0)
  const int wg = blockIdx.x;
  const int swz = (wg & 7) * 64 + (wg >> 3);
  const int bm0 = (swz & 31) * 256;  // 32 M-tiles
  const int bn0 = (swz >> 5) * 256;  // 16 N-tiles

  // ds_read fragment offsets (within a buffer): + ks*16384 + mi(nj)*256
  const int aoff = (lane >> 4) * 4096 + (wm * 128 + r16) * 16;
  const int boff = (lane >> 4) * 4096 + (wn * 64 + r16) * 16;

  // staging source rows: thread covers slots tid and tid+512 (kc and kc+2)
  const bf16* aRow = Xb + (size_t)(bm0 + (tid & 255)) * Kdim + (tid >> 8) * 8;
  const bf16* bRow = Wb + (size_t)(bn0 + (tid & 255)) * Kdim + (tid >> 8) * 8;
  const int ldsOff = tid * 16;

  // stage half: kh in {0,1}; dst = abs LDS base of that 16KB half
  auto stageA = [&](int tt, int kh, char* dst) {
    const bf16* s = aRow + tt * 64 + kh * 32;
    gload_lds16(s, dst + ldsOff);
    gload_lds16(s + 16, dst + ldsOff + 8192);
  };
  auto stageB = [&](int tt, int kh, char* dst) {
    const bf16* s = bRow + tt * 64 + kh * 32;
    gload_lds16(s, dst + ldsOff);
    gload_lds16(s + 16, dst + ldsOff + 8192);
  };
#define ABUF(b) (smem + (b) * 65536)
#define BBUF(b) (smem + (b) * 65536 + 32768)

  f32x4 acc[8][4] = {};

  // prologue: t0 {Ah0,Bh0,Ah1,Bh1}, t1 {Ah0,Bh0}  (12 loads/thread)
  stageA(0, 0, ABUF(0));
  stageB(0, 0, BBUF(0));
  stageA(0, 1, ABUF(0) + 16384);
  stageB(0, 1, BBUF(0) + 16384);
  stageA(1, 0, ABUF(1));
  stageB(1, 0, BBUF(1));

  for (int t = 0; t < 64; ++t) {
    if (t == 63) {
      asm volatile("s_waitcnt vmcnt(0)" ::: "memory");
    } else {
      asm volatile("s_waitcnt vmcnt(4)" ::: "memory");
    }
    __builtin_amdgcn_s_barrier();
    char* Ab = ABUF(t & 1);
    char* Bb = BBUF(t & 1);
    bf16x8 a[8], b0, b1;

    // ---- phase 0: ks=0, nj 0-1; stage (t+1) A-k1
#pragma unroll
    for (int mi = 0; mi < 8; ++mi)
      a[mi] = *reinterpret_cast<const bf16x8*>(Ab + aoff + mi * 256);
    b0 = *reinterpret_cast<const bf16x8*>(Bb + boff + 0 * 256);
    b1 = *reinterpret_cast<const bf16x8*>(Bb + boff + 1 * 256);
    if (t < 63) stageA(t + 1, 1, ABUF((t + 1) & 1) + 16384);
    PHASE_TAIL(0, 1)

    // ---- phase 1: ks=0, nj 2-3; stage (t+1) B-k1
    b0 = *reinterpret_cast<const bf16x8*>(Bb + boff + 2 * 256);
    b1 = *reinterpret_cast<const bf16x8*>(Bb + boff + 3 * 256);
    if (t < 63) stageB(t + 1, 1, BBUF((t + 1) & 1) + 16384);
    PHASE_TAIL(2, 3)

    // ---- phase 2: ks=1, nj 0-1; stage (t+2) A-k0 (region released after ph1)
#pragma unroll
    for (int mi = 0; mi < 8; ++mi)
      a[mi] = *reinterpret_cast<const bf16x8*>(Ab + 16384 + aoff + mi * 256);
    b0 = *reinterpret_cast<const bf16x8*>(Bb + 16384 + boff + 0 * 256);
    b1 = *reinterpret_cast<const bf16x8*>(Bb + 16384 + boff + 1 * 256);
    if (t < 62) stageA(t + 2, 0, ABUF(t & 1));
    PHASE_TAIL(0, 1)

    // ---- phase 3: ks=1, nj 2-3; stage (t+2) B-k0
    b0 = *reinterpret_cast<const bf16x8*>(Bb + 16384 + boff + 2 * 256);
    b1 = *reinterpret_cast<const bf16x8*>(Bb + 16384 + boff + 3 * 256);
    if (t < 62) stageB(t + 2, 0, BBUF(t & 1));
    PHASE_TAIL(2, 3)
  }

  // epilogue: C/D map col=lane&15, row=(lane>>4)*4+reg
  const int crow0 = bm0 + wm * 128 + (lane >> 4) * 4;
  const int ccol0 = bn0 + wn * 64 + r16;
#pragma unroll
  for (int nj = 0; nj < 4; ++nj) {
    float bv = bias[ccol0 + nj * 16];
#pragma unroll
    for (int mi = 0; mi < 8; ++mi)
#pragma unroll
      for (int r = 0; r < 4; ++r)
        out[(size_t)(crow0 + mi * 16 + r) * Ndim + ccol0 + nj * 16] =
            acc[mi][nj][r] + bv;
  }
#undef ABUF
#undef BBUF
}

// ---------------- fallback (ws too small): fp32 tiled GEMM, fold on stage ----------------
__global__ __launch_bounds__(256) void gemm_fallback(const float* __restrict__ x,
                                                     const float* __restrict__ W,
                                                     const float* __restrict__ bias,
                                                     const float* __restrict__ lA,
                                                     const float* __restrict__ lB,
                                                     float* __restrict__ out) {
  __shared__ float xs[16][64];
  __shared__ float wt[16][64];
  const int t = threadIdx.x;
  const int tx = t & 15, ty = t >> 4;
  const int bm0 = blockIdx.y * 64, bn0 = blockIdx.x * 64;
  float acc[4][4] = {};
  for (int kt = 0; kt < Kdim; kt += 16) {
    __syncthreads();
    for (int e = t; e < 1024; e += 256) {
      int m = e >> 4, k = e & 15;
      xs[k][m] = x[(size_t)(bm0 + m) * Kdim + kt + k];
    }
    for (int e = t; e < 1024; e += 256) {
      int n = e >> 4, k = e & 15;
      float v = W[(size_t)(bn0 + n) * Kdim + kt + k];
#pragma unroll
      for (int r = 0; r < 16; ++r)
        v += LORA_SCALE * lB[(bn0 + n) * 16 + r] * lA[r * Kdim + kt + k];
      wt[k][n] = v;
    }
    __syncthreads();
#pragma unroll
    for (int k = 0; k < 16; ++k) {
      float xa[4], wv[4];
#pragma unroll
      for (int i = 0; i < 4; ++i) xa[i] = xs[k][ty * 4 + i];
#pragma unroll
      for (int j = 0; j < 4; ++j) wv[j] = wt[k][tx * 4 + j];
#pragma unroll
      for (int i = 0; i < 4; ++i)
#pragma unroll
        for (int j = 0; j < 4; ++j) acc[i][j] += xa[i] * wv[j];
    }
  }
#pragma unroll
  for (int i = 0; i < 4; ++i)
#pragma unroll
    for (int j = 0; j < 4; ++j)
      out[(size_t)(bm0 + ty * 4 + i) * Ndim + bn0 + tx * 4 + j] =
          acc[i][j] + bias[bn0 + tx * 4 + j];
}

extern "C" void kernel_launch(void* const* d_in, const int* in_sizes, int n_in,
                              void* d_out, int out_size, void* d_ws, size_t ws_size,
                              hipStream_t stream) {
  const float* x = (const float*)d_in[0];
  const float* W = (const float*)d_in[1];
  const float* b = (const float*)d_in[2];
  const float* lA = (const float*)d_in[3];
  const float* lB = (const float*)d_in[4];
  float* out = (float*)d_out;

  const size_t xb_bytes = (size_t)Mdim * Kdim * sizeof(bf16);
  const size_t wb_bytes = (size_t)Ndim * Kdim * sizeof(bf16);

  if (ws_size >= xb_bytes + wb_bytes) {
    bf16* xb = (bf16*)d_ws;
    bf16* wb = (bf16*)((char*)d_ws + xb_bytes);
    cvt_x_kernel<<<4096, 256, 0, stream>>>(x, xb, Mdim * Kdim / 8);
    build_w_kernel<<<Ndim / 8, 256, 0, stream>>>(W, lA, lB, wb);
    (void)hipFuncSetAttribute((const void*)gemm8,
                              hipFuncAttributeMaxDynamicSharedMemorySize, 131072);
    gemm8<<<dim3((Mdim / 256) * (Ndim / 256)), dim3(512), 131072, stream>>>(xb, wb, b,
                                                                            out);
  } else {
    dim3 grid(Ndim / 64, Mdim / 64);
    gemm_fallback<<<grid, 64 * 4, 0, stream>>>(x, W, b, lA, lB, out);
  }
}

// Round 5
// 443.090 us; speedup vs baseline: 1.3359x; 1.0037x over previous
//
#include <hip/hip_runtime.h>

// LoRALinear: out = x @ (W + 2 * B@A)^T + b
// Fold LoRA into W' (bf16), convert x to bf16, one 256x256-tile 8-phase MFMA GEMM.

static constexpr int Mdim = 8192;
static constexpr int Ndim = 4096;
static constexpr int Kdim = 4096;
#define LORA_SCALE 2.0f   // alpha/rank = 32/16

typedef __bf16 bf16;
typedef __bf16 bf16x8 __attribute__((ext_vector_type(8)));
typedef __bf16 bf16x4 __attribute__((ext_vector_type(4)));
typedef float f32x4 __attribute__((ext_vector_type(4)));

__device__ __forceinline__ void gload_lds16(const void* g, void* l) {
  __builtin_amdgcn_global_load_lds(
      (const __attribute__((address_space(1))) unsigned int*)g,
      (__attribute__((address_space(3))) unsigned int*)l, 16, 0, 0);
}

// ---------------- kernel 1: x fp32 -> bf16 ----------------
__global__ __launch_bounds__(256) void cvt_x_kernel(const float* __restrict__ x,
                                                    bf16* __restrict__ xb, int n8) {
  for (int i = blockIdx.x * blockDim.x + threadIdx.x; i < n8;
       i += gridDim.x * blockDim.x) {
    const float4* p = reinterpret_cast<const float4*>(x) + (size_t)i * 2;
    float4 a = p[0];
    float4 c = p[1];
    bf16x8 o;
    o[0] = (bf16)a.x; o[1] = (bf16)a.y; o[2] = (bf16)a.z; o[3] = (bf16)a.w;
    o[4] = (bf16)c.x; o[5] = (bf16)c.y; o[6] = (bf16)c.z; o[7] = (bf16)c.w;
    reinterpret_cast<bf16x8*>(xb)[i] = o;
  }
}

// ---------------- kernel 2: W' = W + 2*B@A  (bf16) ----------------
__global__ __launch_bounds__(256) void build_w_kernel(const float* __restrict__ W,
                                                      const float* __restrict__ lA,
                                                      const float* __restrict__ lB,
                                                      bf16* __restrict__ wb) {
  const int n0 = blockIdx.x * 8;
  const int t = threadIdx.x;
  __shared__ float bs[8][16];
  if (t < 128) bs[t >> 4][t & 15] = lB[(n0 + (t >> 4)) * 16 + (t & 15)] * LORA_SCALE;
  __syncthreads();
  for (int k0 = t * 4; k0 < Kdim; k0 += 1024) {
    float4 acc[8];
#pragma unroll
    for (int j = 0; j < 8; ++j)
      acc[j] = *reinterpret_cast<const float4*>(&W[(size_t)(n0 + j) * Kdim + k0]);
#pragma unroll
    for (int r = 0; r < 16; ++r) {
      float4 a = *reinterpret_cast<const float4*>(&lA[r * Kdim + k0]);
#pragma unroll
      for (int j = 0; j < 8; ++j) {
        acc[j].x += bs[j][r] * a.x;
        acc[j].y += bs[j][r] * a.y;
        acc[j].z += bs[j][r] * a.z;
        acc[j].w += bs[j][r] * a.w;
      }
    }
#pragma unroll
    for (int j = 0; j < 8; ++j) {
      bf16x4 o;
      o[0] = (bf16)acc[j].x; o[1] = (bf16)acc[j].y;
      o[2] = (bf16)acc[j].z; o[3] = (bf16)acc[j].w;
      *reinterpret_cast<bf16x4*>(&wb[(size_t)(n0 + j) * Kdim + k0]) = o;
    }
  }
}

// ---------------- kernel 3: 256x256 8-phase bf16 MFMA GEMM ----------------
// 8 waves (2M x 4N), per-wave 128x64 out. BK=64 split in 2 K-halves of 32.
// LDS 128KB: buf{0,1} x { A: [kh][kc][row 0..255][8bf16] 32KB, B: same 32KB }.
// Stage unit = 16KB half (2 gload_lds16/thread). Cadence per tile t:
//   ph0 -> (t+1) A-k1   ph1 -> (t+1) B-k1   ph2 -> (t+2) A-k0   ph3 -> (t+2) B-k0
// Boundary wait vmcnt(4) (2 halves in flight = next tile's k0), vmcnt(0) at t=63.
// sched_barrier(0) BEFORE the opening s_barrier: s_barrier is NOT an LLVM memory
// fence, so without the pin the compiler may sink this phase's ds_reads past the
// barrier, serializing their full latency into the lgkmcnt(0) wait.
#define PHASE_TAIL(NJ0, NJ1)                                                    \
  __builtin_amdgcn_sched_barrier(0);                                            \
  __builtin_amdgcn_s_barrier();                                                 \
  asm volatile("s_waitcnt lgkmcnt(0)" ::: "memory");                            \
  __builtin_amdgcn_sched_barrier(0);                                            \
  __builtin_amdgcn_s_setprio(1);                                                \
  _Pragma("unroll")                                                             \
  for (int mi = 0; mi < 8; ++mi) {                                              \
    acc[mi][NJ0] = __builtin_amdgcn_mfma_f32_16x16x32_bf16(a[mi], b0,           \
                                                           acc[mi][NJ0], 0, 0, 0); \
    acc[mi][NJ1] = __builtin_amdgcn_mfma_f32_16x16x32_bf16(a[mi], b1,           \
                                                           acc[mi][NJ1], 0, 0, 0); \
  }                                                                             \
  __builtin_amdgcn_s_setprio(0);                                                \
  __builtin_amdgcn_s_barrier();

__global__ __launch_bounds__(512, 2) void gemm8(const bf16* __restrict__ Xb,
                                                const bf16* __restrict__ Wb,
                                                const float* __restrict__ bias,
                                                float* __restrict__ out) {
  extern __shared__ char smem[];  // 131072 bytes
  const int tid = threadIdx.x;
  const int lane = tid & 63;
  const int wid = tid >> 6;
  const int wm = wid >> 2, wn = wid & 3;  // 2 x 4 wave grid
  const int r16 = lane & 15;

  // XCD-aware bijective swizzle (512 wgs, 512 % 8 == 0)
  const int wg = blockIdx.x;
  const int swz = (wg & 7) * 64 + (wg >> 3);
  const int bm0 = (swz & 31) * 256;  // 32 M-tiles
  const int bn0 = (swz >> 5) * 256;  // 16 N-tiles

  // ds_read fragment offsets (within a buffer): + ks*16384 + mi(nj)*256
  const int aoff = (lane >> 4) * 4096 + (wm * 128 + r16) * 16;
  const int boff = (lane >> 4) * 4096 + (wn * 64 + r16) * 16;

  // staging source rows: thread covers slots tid and tid+512 (kc and kc+2)
  const bf16* aRow = Xb + (size_t)(bm0 + (tid & 255)) * Kdim + (tid >> 8) * 8;
  const bf16* bRow = Wb + (size_t)(bn0 + (tid & 255)) * Kdim + (tid >> 8) * 8;
  const int ldsOff = tid * 16;

  // stage half: kh in {0,1}; dst = abs LDS base of that 16KB half
  auto stageA = [&](int tt, int kh, char* dst) {
    const bf16* s = aRow + tt * 64 + kh * 32;
    gload_lds16(s, dst + ldsOff);
    gload_lds16(s + 16, dst + ldsOff + 8192);
  };
  auto stageB = [&](int tt, int kh, char* dst) {
    const bf16* s = bRow + tt * 64 + kh * 32;
    gload_lds16(s, dst + ldsOff);
    gload_lds16(s + 16, dst + ldsOff + 8192);
  };
#define ABUF(b) (smem + (b) * 65536)
#define BBUF(b) (smem + (b) * 65536 + 32768)

  f32x4 acc[8][4] = {};

  // prologue: t0 {Ah0,Bh0,Ah1,Bh1}, t1 {Ah0,Bh0}  (12 loads/thread)
  stageA(0, 0, ABUF(0));
  stageB(0, 0, BBUF(0));
  stageA(0, 1, ABUF(0) + 16384);
  stageB(0, 1, BBUF(0) + 16384);
  stageA(1, 0, ABUF(1));
  stageB(1, 0, BBUF(1));

  for (int t = 0; t < 64; ++t) {
    if (t == 63) {
      asm volatile("s_waitcnt vmcnt(0)" ::: "memory");
    } else {
      asm volatile("s_waitcnt vmcnt(4)" ::: "memory");
    }
    __builtin_amdgcn_s_barrier();
    char* Ab = ABUF(t & 1);
    char* Bb = BBUF(t & 1);
    bf16x8 a[8], b0, b1;

    // ---- phase 0: ks=0, nj 0-1; stage (t+1) A-k1 (issued first: max flight time)
    if (t < 63) stageA(t + 1, 1, ABUF((t + 1) & 1) + 16384);
#pragma unroll
    for (int mi = 0; mi < 8; ++mi)
      a[mi] = *reinterpret_cast<const bf16x8*>(Ab + aoff + mi * 256);
    b0 = *reinterpret_cast<const bf16x8*>(Bb + boff + 0 * 256);
    b1 = *reinterpret_cast<const bf16x8*>(Bb + boff + 1 * 256);
    PHASE_TAIL(0, 1)

    // ---- phase 1: ks=0, nj 2-3; stage (t+1) B-k1
    if (t < 63) stageB(t + 1, 1, BBUF((t + 1) & 1) + 16384);
    b0 = *reinterpret_cast<const bf16x8*>(Bb + boff + 2 * 256);
    b1 = *reinterpret_cast<const bf16x8*>(Bb + boff + 3 * 256);
    PHASE_TAIL(2, 3)

    // ---- phase 2: ks=1, nj 0-1; stage (t+2) A-k0 (region released after ph1)
    if (t < 62) stageA(t + 2, 0, ABUF(t & 1));
#pragma unroll
    for (int mi = 0; mi < 8; ++mi)
      a[mi] = *reinterpret_cast<const bf16x8*>(Ab + 16384 + aoff + mi * 256);
    b0 = *reinterpret_cast<const bf16x8*>(Bb + 16384 + boff + 0 * 256);
    b1 = *reinterpret_cast<const bf16x8*>(Bb + 16384 + boff + 1 * 256);
    PHASE_TAIL(0, 1)

    // ---- phase 3: ks=1, nj 2-3; stage (t+2) B-k0
    if (t < 62) stageB(t + 2, 0, BBUF(t & 1));
    b0 = *reinterpret_cast<const bf16x8*>(Bb + 16384 + boff + 2 * 256);
    b1 = *reinterpret_cast<const bf16x8*>(Bb + 16384 + boff + 3 * 256);
    PHASE_TAIL(2, 3)
  }

  // epilogue: C/D map col=lane&15, row=(lane>>4)*4+reg
  const int crow0 = bm0 + wm * 128 + (lane >> 4) * 4;
  const int ccol0 = bn0 + wn * 64 + r16;
#pragma unroll
  for (int nj = 0; nj < 4; ++nj) {
    float bv = bias[ccol0 + nj * 16];
#pragma unroll
    for (int mi = 0; mi < 8; ++mi)
#pragma unroll
      for (int r = 0; r < 4; ++r)
        out[(size_t)(crow0 + mi * 16 + r) * Ndim + ccol0 + nj * 16] =
            acc[mi][nj][r] + bv;
  }
#undef ABUF
#undef BBUF
}

// ---------------- fallback (ws too small): fp32 tiled GEMM, fold on stage ----------------
__global__ __launch_bounds__(256) void gemm_fallback(const float* __restrict__ x,
                                                     const float* __restrict__ W,
                                                     const float* __restrict__ bias,
                                                     const float* __restrict__ lA,
                                                     const float* __restrict__ lB,
                                                     float* __restrict__ out) {
  __shared__ float xs[16][64];
  __shared__ float wt[16][64];
  const int t = threadIdx.x;
  const int tx = t & 15, ty = t >> 4;
  const int bm0 = blockIdx.y * 64, bn0 = blockIdx.x * 64;
  float acc[4][4] = {};
  for (int kt = 0; kt < Kdim; kt += 16) {
    __syncthreads();
    for (int e = t; e < 1024; e += 256) {
      int m = e >> 4, k = e & 15;
      xs[k][m] = x[(size_t)(bm0 + m) * Kdim + kt + k];
    }
    for (int e = t; e < 1024; e += 256) {
      int n = e >> 4, k = e & 15;
      float v = W[(size_t)(bn0 + n) * Kdim + kt + k];
#pragma unroll
      for (int r = 0; r < 16; ++r)
        v += LORA_SCALE * lB[(bn0 + n) * 16 + r] * lA[r * Kdim + kt + k];
      wt[k][n] = v;
    }
    __syncthreads();
#pragma unroll
    for (int k = 0; k < 16; ++k) {
      float xa[4], wv[4];
#pragma unroll
      for (int i = 0; i < 4; ++i) xa[i] = xs[k][ty * 4 + i];
#pragma unroll
      for (int j = 0; j < 4; ++j) wv[j] = wt[k][tx * 4 + j];
#pragma unroll
      for (int i = 0; i < 4; ++i)
#pragma unroll
        for (int j = 0; j < 4; ++j) acc[i][j] += xa[i] * wv[j];
    }
  }
#pragma unroll
  for (int i = 0; i < 4; ++i)
#pragma unroll
    for (int j = 0; j < 4; ++j)
      out[(size_t)(bm0 + ty * 4 + i) * Ndim + bn0 + tx * 4 + j] =
          acc[i][j] + bias[bn0 + tx * 4 + j];
}

extern "C" void kernel_launch(void* const* d_in, const int* in_sizes, int n_in,
                              void* d_out, int out_size, void* d_ws, size_t ws_size,
                              hipStream_t stream) {
  const float* x = (const float*)d_in[0];
  const float* W = (const float*)d_in[1];
  const float* b = (const float*)d_in[2];
  const float* lA = (const float*)d_in[3];
  const float* lB = (const float*)d_in[4];
  float* out = (float*)d_out;

  const size_t xb_bytes = (size_t)Mdim * Kdim * sizeof(bf16);
  const size_t wb_bytes = (size_t)Ndim * Kdim * sizeof(bf16);

  if (ws_size >= xb_bytes + wb_bytes) {
    bf16* xb = (bf16*)d_ws;
    bf16* wb = (bf16*)((char*)d_ws + xb_bytes);
    cvt_x_kernel<<<4096, 256, 0, stream>>>(x, xb, Mdim * Kdim / 8);
    build_w_kernel<<<Ndim / 8, 256, 0, stream>>>(W, lA, lB, wb);
    (void)hipFuncSetAttribute((const void*)gemm8,
                              hipFuncAttributeMaxDynamicSharedMemorySize, 131072);
    gemm8<<<dim3((Mdim / 256) * (Ndim / 256)), dim3(512), 131072, stream>>>(xb, wb, b,
                                                                            out);
  } else {
    dim3 grid(Ndim / 64, Mdim / 64);
    gemm_fallback<<<grid, 64 * 4, 0, stream>>>(x, W, b, lA, lB, out);
  }
}